// Round 15
// baseline (5999.210 us; speedup 1.0000x reference)
//
#include <hip/hip_runtime.h>
#include <stdint.h>

#define NSTEP 365
#define NGRID 4000
#define CAPMIN 0.00125f
#define SMINV 0.0001f
#define PSTR_DW (NGRID * 88)
#define XSTR_DW (NGRID * 3)

// r9 LDS layout (dwords), total 16000 dw = 64000 B
#define RAW_SLOT 384
#define RAW_REG  (5 * RAW_SLOT)
#define DER_BASE 7680
#define DER_SLOT 768
#define DER_REG  (5 * DER_SLOT)
#define SMQ_BASE 15360
#define SME_BASE 15680

typedef __attribute__((address_space(3))) uint32_t lds_u32_t;
typedef __attribute__((address_space(1))) uint32_t glb_u32_t;

__device__ __forceinline__ void dma4(const float* g, float* l) {
    __builtin_amdgcn_global_load_lds((const glb_u32_t*)(const void*)g,
                                     (lds_u32_t*)(void*)l, 4, 0, 0);
}

__device__ __forceinline__ float frcp(float x) { return __builtin_amdgcn_rcpf(x); }
__device__ __forceinline__ float fexp2(float x) { return __builtin_amdgcn_exp2f(x); }
__device__ __forceinline__ float flog2(float x) { return __builtin_amdgcn_logf(x); }

__device__ __forceinline__ void issue_slot(const float* pp, const float* px,
                                           int t, float* dst) {
    const float* pj = pp + (size_t)t * PSTR_DW;
    dma4(pj,      dst);
    dma4(pj + 8,  dst + 64);
    dma4(pj + 16, dst + 128);
    dma4(pj + 24, dst + 192);
    dma4(pj + 32, dst + 256);
    dma4(px + (size_t)t * XSTR_DW, dst + 320);
}

// ======== r9 fat state macros (main kernel + skel/slim comparisons) ========
#define RDS9(j)                                                              \
    const float  c0_##j = rreg[(j) * RAW_SLOT + lane];                       \
    const float  kz_##j = rreg[(j) * RAW_SLOT + 256 + lane];                 \
    const float  Pp_##j = rreg[(j) * RAW_SLOT + 320 + gl3];                  \
    const float  Ee_##j = rreg[(j) * RAW_SLOT + 322 + gl3];                  \
    const float2 dA_##j = dreg[(j) * 384 + lane];                            \
    const float2 dB_##j = dreg[(j) * 384 + 64 + lane];                       \
    const float2 dC_##j = dreg[(j) * 384 + 128 + lane];                      \
    const float2 dD_##j = dreg[(j) * 384 + 192 + lane];                      \
    const float2 dE_##j = dreg[(j) * 384 + 256 + lane];                      \
    const float2 dF_##j = dreg[(j) * 384 + 320 + lane];

#define STEP9(j) do {                                                        \
    const float uztwm = dA_##j.x, uzfwm = dA_##j.y;                          \
    const float inv_uztwm = dB_##j.x, inv_uzfwm = dB_##j.y;                  \
    const float inv_uzsum = dC_##j.x, lztwm = dC_##j.y;                      \
    const float inv_lztwm = dD_##j.x, pbase = dD_##j.y;                      \
    const float lzfwpm = dE_##j.x, lzfwsm = dE_##j.y;                        \
    const float pz = dF_##j.x, inv_defmax = dF_##j.y;                        \
    const float Ep = Ee_##j, kuz = kz_##j;                                   \
    const float qdir = c0_##j * Pp_##j;                                      \
    const float peff = Pp_##j - qdir;                                        \
    const float rud  = S2 * uztwm - S1 * uzfwm;                              \
    const float ru   = (rud > 0.0f) ? rud * inv_uzsum : 0.0f;                \
    const float euztw = fminf(S1 * inv_uztwm * Ep, S1);                      \
    const float twexu = (S1 >= uztwm) ? peff : 0.0f;                         \
    const float qsur  = (S2 >= uzfwm) ? twexu : 0.0f;                        \
    const float qint  = kuz * S2;                                            \
    const float euzfw = fminf(fmaxf(0.0f, Ep - euztw), S2);                  \
    const float deficit = fmaxf(1e-8f, lztwm - S3)                           \
                        + fmaxf(1e-8f, lzfwpm - S4)                          \
                        + fmaxf(1e-8f, lzfwsm - S5);                         \
    const float powterm = fexp2(e1 * flog2(deficit * inv_defmax));           \
    const float pc = fminf((pbase + pz * powterm) * (S2 * inv_uzfwm), S2);   \
    const float pctw = (1.0f - pfree) * pc;                                  \
    const float ev3 = fmaxf(0.0f, Ep - euztw - euzfw);                       \
    const float elztw = fminf(S3 * inv_lztwm * ev3, S3);                     \
    const float twexl = (S3 >= lztwm) ? pctw : 0.0f;                         \
    const float aa = fmaxf(0.0f, lzfwpm - S4) * lzfwsm;                      \
    const float bb = fmaxf(0.0f, lzfwsm - S5) * lzfwpm;                      \
    const float den = aa + bb;                                               \
    const float pm = lzfwpm + lzfwsm;                                        \
    const float fp = ((den > 0.0f) ? aa : lzfwpm)                            \
                   * frcp((den > 0.0f) ? den : pm);                          \
    const float fs = 1.0f - fp;                                              \
    const float twexlp = fp * twexl, twexls = fs * twexl;                    \
    const float pcfwp = pfree * fp * pc, pcfws = pfree * fs * pc;            \
    const bool rlm = S3 * pm < (S4 + S5) * lztwm;                            \
    const float rlp = rlm ? (S4 * lztwm - S3 * lzfwpm) * inv_defmax : 0.0f;  \
    const float rls = rlm ? (S5 * lztwm - S3 * lzfwsm) * inv_defmax : 0.0f;  \
    const float qbfp = klzp * S4, qbfs = klzs * S5;                          \
    S1 = fmaxf(S1 + peff + ru - euztw - twexu, SMINV);                       \
    S2 = fmaxf(S2 + twexu - euzfw - qsur - qint - ru - pc, SMINV);           \
    S3 = fmaxf(S3 + pctw + rlp + rls - elztw - twexl, SMINV);                \
    S4 = fmaxf(S4 + twexlp + pcfwp - rlp - qbfp, SMINV);                     \
    S5 = fmaxf(S5 + twexls + pcfws - rls - qbfs, SMINV);                     \
    smq[(j) * 64 + lane] = qdir + qsur + qint + qbfp + qbfs;                 \
    sme[(j) * 64 + lane] = euztw + euzfw + elztw;                            \
} while (0)

#define STEPSK(j) do {                                                       \
    S1 += c0_##j * 0.1f + dA_##j.x;                                          \
    S2 += kz_##j + dB_##j.y;                                                 \
    S3 += Pp_##j + dC_##j.x + dD_##j.y;                                      \
    S4 += Ee_##j + dE_##j.x + dF_##j.y;                                      \
    S5 += dA_##j.y + dB_##j.x + dC_##j.y + dD_##j.x + dE_##j.y + dF_##j.x;   \
    smq[(j) * 64 + lane] = S1 + S2;                                          \
    sme[(j) * 64 + lane] = S3 + S4 + S5;                                     \
} while (0)

// ======== r14 slim 7-row macros (isolation probe only) ========
#define RDSL(j)                                                              \
    const float2 qp_##j = dregL[(j) * 448 + lane];                           \
    const float2 ek_##j = dregL[(j) * 448 +  64 + lane];                     \
    const float2 iu_##j = dregL[(j) * 448 + 128 + lane];                     \
    const float2 hl_##j = dregL[(j) * 448 + 192 + lane];                     \
    const float2 ip_##j = dregL[(j) * 448 + 256 + lane];                     \
    const float2 lz_##j = dregL[(j) * 448 + 320 + lane];                     \
    const float2 pzv_##j = dregL[(j) * 448 + 384 + lane];

#define STEPL(j) do {                                                        \
    const float qdir = qp_##j.x, peff = qp_##j.y;                            \
    const float Ep = ek_##j.x, kuz = ek_##j.y;                               \
    const float inv_uztwm = iu_##j.x, inv_uzfwm = iu_##j.y;                  \
    const float hmean = hl_##j.x, lztwm = hl_##j.y;                          \
    const float inv_lztwm = ip_##j.x, pbase = ip_##j.y;                      \
    const float lzfwpm = lz_##j.x, lzfwsm = lz_##j.y;                        \
    const float pz = pzv_##j.x, inv_defmax = pzv_##j.y;                      \
    const float r1 = S1 * inv_uztwm;                                         \
    const float r2 = S2 * inv_uzfwm;                                         \
    const float euztw = fminf(r1 * Ep, S1);                                  \
    const float twexu = (r1 >= 1.0f) ? peff : 0.0f;                          \
    const float qsur  = (r2 >= 1.0f) ? twexu : 0.0f;                         \
    const float rd = r2 - r1;                                                \
    const float ru = (rd > 0.0f) ? rd * hmean : 0.0f;                        \
    const float qint = kuz * S2;                                             \
    const float euzfw = fminf(fmaxf(0.0f, Ep - euztw), S2);                  \
    const float t3 = lztwm - S3, t4 = lzfwpm - S4, t5 = lzfwsm - S5;         \
    const float deficit = fmaxf(1e-8f, t3) + fmaxf(1e-8f, t4)                \
                        + fmaxf(1e-8f, t5);                                  \
    const float powterm = fexp2(e1 * flog2(deficit * inv_defmax));           \
    const float pc = fminf((pbase + pz * powterm) * r2, S2);                 \
    const float pctw = pfree1m * pc;                                         \
    const float ev3 = fmaxf(0.0f, Ep - euztw - euzfw);                       \
    const float elztw = fminf(S3 * inv_lztwm * ev3, S3);                     \
    const float twexl = (S3 >= lztwm) ? pctw : 0.0f;                         \
    const float aa = fmaxf(0.0f, t4) * lzfwsm;                               \
    const float bb = fmaxf(0.0f, t5) * lzfwpm;                               \
    const float den = aa + bb;                                               \
    const float pm = lzfwpm + lzfwsm;                                        \
    const float fp = ((den > 0.0f) ? aa : lzfwpm)                            \
                   * frcp((den > 0.0f) ? den : pm);                          \
    const float fs = 1.0f - fp;                                              \
    const float pcp = pfree * pc;                                            \
    const float twexlp = fp * twexl, twexls = fs * twexl;                    \
    const float pcfwp = fp * pcp, pcfws = fs * pcp;                          \
    const bool rlm = S3 * pm < (S4 + S5) * lztwm;                            \
    const float rlp = rlm ? (S4 * lztwm - S3 * lzfwpm) * inv_defmax : 0.0f;  \
    const float rls = rlm ? (S5 * lztwm - S3 * lzfwsm) * inv_defmax : 0.0f;  \
    const float qbfp = klzp * S4, qbfs = klzs * S5;                          \
    S1 = fmaxf(S1 + peff + ru - euztw - twexu, SMINV);                       \
    S2 = fmaxf(S2 + twexu - euzfw - qsur - qint - ru - pc, SMINV);           \
    S3 = fmaxf(S3 + pctw + rlp + rls - elztw - twexl, SMINV);                \
    S4 = fmaxf(S4 + twexlp + pcfwp - rlp - qbfp, SMINV);                     \
    S5 = fmaxf(S5 + twexls + pcfws - rls - qbfs, SMINV);                     \
    smq[(j) * 64 + lane] = qdir + qsur + qint + qbfp + qbfs;                 \
    sme[(j) * 64 + lane] = euztw + euzfw + elztw;                            \
} while (0)

// ===================== MAIN KERNEL: r9 verbatim (106.5 us) =====================
__global__ __launch_bounds__(192, 1) void sacsma_kernel(
    const float* __restrict__ x, const float* __restrict__ par,
    float* __restrict__ out)
{
    __shared__ __align__(16) float lds[16000];

    const int wave = threadIdx.x >> 6;
    const int lane = threadIdx.x & 63;
    const int g0   = blockIdx.x * 8;
    const int gl   = lane >> 3;
    const int mu   = lane & 7;
    const int g    = g0 + gl;

    if (wave == 0) {
        const float* pp = par + (size_t)g * 88 + mu;
        int xl = lane; if (xl >= 24) xl -= 24; if (xl >= 24) xl -= 24;
        const int xq = xl / 3;
        const float* px = x + (g0 + xq) * 3 + (xl - xq * 3);

        #pragma unroll
        for (int j = 0; j < 5; ++j)
            issue_slot(pp, px, j, lds + j * RAW_SLOT);

        for (int i = 0; i < 75; ++i) {
            if (i <= 71) {
                const int b = i + 1;
                float* dst = lds + (b & 3) * RAW_REG;
                const int tb = 5 * b;
                #pragma unroll
                for (int j = 0; j < 5; ++j)
                    issue_slot(pp, px, tb + j, dst + j * RAW_SLOT);
                asm volatile("s_waitcnt vmcnt(30)" ::: "memory");
            } else {
                asm volatile("s_waitcnt vmcnt(0)" ::: "memory");
            }
            asm volatile("s_barrier" ::: "memory");
        }
    } else if (wave == 1) {
        const float* ps = par + ((size_t)(NSTEP - 1) * NGRID + g) * 88 + mu;
        const float f3   = 0.005f + ps[6 * 8] * 0.99f;
        const float f4   = 0.005f + ps[7 * 8] * 0.99f;
        const float klzp = ps[9 * 8];
        const float klzs = ps[10 * 8];

        for (int i = 0; i < 75; ++i) {
            if (i >= 1 && i <= 73) {
                const int b = i - 1;
                const float* rreg = lds + (b & 3) * RAW_REG;
                float* dregf = lds + DER_BASE + (b & 1) * DER_REG;
                #pragma unroll
                for (int j = 0; j < 5; ++j) {
                    const float* rb = rreg + j * RAW_SLOT;
                    float2* db = reinterpret_cast<float2*>(dregf + j * DER_SLOT);
                    const float c1 = rb[64 + lane];
                    const float c2 = rb[128 + lane];
                    const float c3 = rb[192 + lane];
                    const float smaxv = 1.0f + c1 * 1999.0f;
                    const float f1 = 0.005f + c2 * 0.99f;
                    const float f2 = 0.005f + c3 * 0.99f;
                    const float uztwm = f1 * smaxv;
                    float rem = smaxv - uztwm;
                    const float uzfwm = fmaxf(CAPMIN, f2 * rem);
                    rem -= uzfwm;
                    const float lztwm = fmaxf(CAPMIN, f3 * rem);
                    rem -= lztwm;
                    const float lzfwpm = fmaxf(CAPMIN, f4 * rem);
                    const float lzfwsm = fmaxf(CAPMIN, (1.0f - f4) * rem);
                    const float pbase = lzfwpm * klzp + lzfwsm * klzs;
                    const float pz = fminf(lztwm + lzfwsm * (1.0f - klzs)
                                           + lzfwpm * (1.0f - klzp),
                                           100000.0f * pbase);
                    const float inv_uztwm = frcp(uztwm);
                    const float inv_uzfwm = frcp(uzfwm);
                    const float inv_lztwm = frcp(lztwm);
                    const float inv_uzsum = frcp(uztwm + uzfwm);
                    const float inv_defmax = frcp(lztwm + lzfwpm + lzfwsm);
                    db[0 * 64 + lane] = make_float2(uztwm, uzfwm);
                    db[1 * 64 + lane] = make_float2(inv_uztwm, inv_uzfwm);
                    db[2 * 64 + lane] = make_float2(inv_uzsum, lztwm);
                    db[3 * 64 + lane] = make_float2(inv_lztwm, pbase);
                    db[4 * 64 + lane] = make_float2(lzfwpm, lzfwsm);
                    db[5 * 64 + lane] = make_float2(pz, inv_defmax);
                }
                asm volatile("s_waitcnt lgkmcnt(0)" ::: "memory");
            }
            asm volatile("s_barrier" ::: "memory");
        }
    } else {
        const float* ps = par + ((size_t)(NSTEP - 1) * NGRID + g) * 88 + mu;
        const float e1    = 1.0f + ps[5 * 8] * 7.0f;
        const float pfree = ps[8 * 8];
        const float klzp  = ps[9 * 8];
        const float klzs  = ps[10 * 8];

        float S1 = 0.001f, S2 = 0.001f, S3 = 0.001f, S4 = 0.001f, S5 = 0.001f;
        float* smq = lds + SMQ_BASE;
        float* sme = lds + SME_BASE;
        const int gl3 = gl * 3;

        for (int i = 0; i < 75; ++i) {
            if (i >= 2) {
                const int b = i - 2;
                const float* rreg = lds + (b & 3) * RAW_REG;
                const float2* dreg = reinterpret_cast<const float2*>(
                    lds + DER_BASE + (b & 1) * DER_REG);

                RDS9(0) RDS9(1) RDS9(2) RDS9(3) RDS9(4)
                STEP9(0); STEP9(1); STEP9(2); STEP9(3); STEP9(4);

                if (lane < 40) {
                    const int s  = lane >> 3;
                    const int gg = lane & 7;
                    const float4* q4 = reinterpret_cast<const float4*>(&smq[s * 64 + gg * 8]);
                    const float4* e4 = reinterpret_cast<const float4*>(&sme[s * 64 + gg * 8]);
                    const float4 qa = q4[0], qb = q4[1];
                    const float4 ea = e4[0], eb = e4[1];
                    const float qsum = ((qa.x + qa.y) + (qa.z + qa.w))
                                     + ((qb.x + qb.y) + (qb.z + qb.w));
                    const float esum = ((ea.x + ea.y) + (ea.z + ea.w))
                                     + ((eb.x + eb.y) + (eb.z + eb.w));
                    float2 o = make_float2(qsum * 0.125f, esum * 0.125f);
                    *reinterpret_cast<float2*>(
                        out + ((size_t)(5 * b + s) * NGRID + g0 + gg) * 2) = o;
                }
            }
            asm volatile("s_barrier" ::: "memory");
        }
    }
}

// ============ PROBE A: r9 skeleton, trivial state math, x16 ============
__global__ __launch_bounds__(192, 1) void probe_skel(
    const float* __restrict__ x, const float* __restrict__ par,
    float* __restrict__ ws, int wsok)
{
    __shared__ __align__(16) float lds[16000];

    const int wave = threadIdx.x >> 6;
    const int lane = threadIdx.x & 63;
    const int g0   = blockIdx.x * 8;
    const int gl   = lane >> 3;
    const int mu   = lane & 7;
    const int g    = g0 + gl;

    if (wave == 0) {
        const float* pp = par + (size_t)g * 88 + mu;
        int xl = lane; if (xl >= 24) xl -= 24; if (xl >= 24) xl -= 24;
        const int xq = xl / 3;
        const float* px = x + (g0 + xq) * 3 + (xl - xq * 3);

        for (int rep = 0; rep < 16; ++rep) {
            #pragma unroll
            for (int j = 0; j < 5; ++j)
                issue_slot(pp, px, j, lds + j * RAW_SLOT);
            for (int i = 0; i < 75; ++i) {
                if (i <= 71) {
                    const int b = i + 1;
                    float* dst = lds + (b & 3) * RAW_REG;
                    const int tb = 5 * b;
                    #pragma unroll
                    for (int j = 0; j < 5; ++j)
                        issue_slot(pp, px, tb + j, dst + j * RAW_SLOT);
                    asm volatile("s_waitcnt vmcnt(30)" ::: "memory");
                } else {
                    asm volatile("s_waitcnt vmcnt(0)" ::: "memory");
                }
                asm volatile("s_barrier" ::: "memory");
            }
        }
    } else if (wave == 1) {
        const float* ps = par + ((size_t)(NSTEP - 1) * NGRID + g) * 88 + mu;
        const float f3   = 0.005f + ps[6 * 8] * 0.99f;
        const float f4   = 0.005f + ps[7 * 8] * 0.99f;
        const float klzp = ps[9 * 8];
        const float klzs = ps[10 * 8];

        for (int rep = 0; rep < 16; ++rep) {
            for (int i = 0; i < 75; ++i) {
                if (i >= 1 && i <= 73) {
                    const int b = i - 1;
                    const float* rreg = lds + (b & 3) * RAW_REG;
                    float* dregf = lds + DER_BASE + (b & 1) * DER_REG;
                    #pragma unroll
                    for (int j = 0; j < 5; ++j) {
                        const float* rb = rreg + j * RAW_SLOT;
                        float2* db = reinterpret_cast<float2*>(dregf + j * DER_SLOT);
                        const float c1 = rb[64 + lane];
                        const float c2 = rb[128 + lane];
                        const float c3 = rb[192 + lane];
                        const float smaxv = 1.0f + c1 * 1999.0f;
                        const float f1 = 0.005f + c2 * 0.99f;
                        const float f2 = 0.005f + c3 * 0.99f;
                        const float uztwm = f1 * smaxv;
                        float rem = smaxv - uztwm;
                        const float uzfwm = fmaxf(CAPMIN, f2 * rem);
                        rem -= uzfwm;
                        const float lztwm = fmaxf(CAPMIN, f3 * rem);
                        rem -= lztwm;
                        const float lzfwpm = fmaxf(CAPMIN, f4 * rem);
                        const float lzfwsm = fmaxf(CAPMIN, (1.0f - f4) * rem);
                        const float pbase = lzfwpm * klzp + lzfwsm * klzs;
                        const float pz = fminf(lztwm + lzfwsm * (1.0f - klzs)
                                               + lzfwpm * (1.0f - klzp),
                                               100000.0f * pbase);
                        const float inv_uztwm = frcp(uztwm);
                        const float inv_uzfwm = frcp(uzfwm);
                        const float inv_lztwm = frcp(lztwm);
                        const float inv_uzsum = frcp(uztwm + uzfwm);
                        const float inv_defmax = frcp(lztwm + lzfwpm + lzfwsm);
                        db[0 * 64 + lane] = make_float2(uztwm, uzfwm);
                        db[1 * 64 + lane] = make_float2(inv_uztwm, inv_uzfwm);
                        db[2 * 64 + lane] = make_float2(inv_uzsum, lztwm);
                        db[3 * 64 + lane] = make_float2(inv_lztwm, pbase);
                        db[4 * 64 + lane] = make_float2(lzfwpm, lzfwsm);
                        db[5 * 64 + lane] = make_float2(pz, inv_defmax);
                    }
                    asm volatile("s_waitcnt lgkmcnt(0)" ::: "memory");
                }
                asm volatile("s_barrier" ::: "memory");
            }
        }
    } else {
        float S1 = 0.001f, S2 = 0.001f, S3 = 0.001f, S4 = 0.001f, S5 = 0.001f;
        float* smq = lds + SMQ_BASE;
        float* sme = lds + SME_BASE;
        const int gl3 = gl * 3;

        for (int rep = 0; rep < 16; ++rep) {
            for (int i = 0; i < 75; ++i) {
                if (i >= 2) {
                    const int b = i - 2;
                    const float* rreg = lds + (b & 3) * RAW_REG;
                    const float2* dreg = reinterpret_cast<const float2*>(
                        lds + DER_BASE + (b & 1) * DER_REG);
                    RDS9(0) RDS9(1) RDS9(2) RDS9(3) RDS9(4)
                    STEPSK(0); STEPSK(1); STEPSK(2); STEPSK(3); STEPSK(4);
                    asm volatile("s_waitcnt lgkmcnt(0)" ::: "memory");
                }
                asm volatile("s_barrier" ::: "memory");
            }
        }
        asm volatile("" :: "v"(S1), "v"(S2), "v"(S3), "v"(S4), "v"(S5));
        if (wsok) ws[(blockIdx.x * 192 + threadIdx.x) & 16383] = S1 + S2 + S3 + S4 + S5;
    }
}

// ============ PROBE B: transform math alone, no barriers, x64 ============
__global__ __launch_bounds__(64, 1) void probe_xform(float* __restrict__ ws, int wsok)
{
    __shared__ __align__(16) float plds[5760];   // raw 1920 | derived 3840

    const int lane = threadIdx.x;
    for (int k = lane; k < 5760; k += 64)
        plds[k] = 0.25f + (float)(k & 63) * 0.01f;
    asm volatile("s_waitcnt lgkmcnt(0)" ::: "memory");

    const float f3 = 0.4f, f4 = 0.5f, klzp = 0.4f, klzs = 0.2f;
    float acc = 0.0f;

    for (int rep = 0; rep < 64; ++rep) {
        for (int i = 0; i < 73; ++i) {
            asm volatile("" ::: "memory");
            const float* rreg = plds;
            float* dregf = plds + 1920;
            #pragma unroll
            for (int j = 0; j < 5; ++j) {
                const float* rb = rreg + j * RAW_SLOT;
                float2* db = reinterpret_cast<float2*>(dregf + j * DER_SLOT);
                const float c1 = rb[64 + lane];
                const float c2 = rb[128 + lane];
                const float c3 = rb[192 + lane];
                const float smaxv = 1.0f + c1 * 1999.0f;
                const float f1 = 0.005f + c2 * 0.99f;
                const float f2 = 0.005f + c3 * 0.99f;
                const float uztwm = f1 * smaxv;
                float rem = smaxv - uztwm;
                const float uzfwm = fmaxf(CAPMIN, f2 * rem);
                rem -= uzfwm;
                const float lztwm = fmaxf(CAPMIN, f3 * rem);
                rem -= lztwm;
                const float lzfwpm = fmaxf(CAPMIN, f4 * rem);
                const float lzfwsm = fmaxf(CAPMIN, (1.0f - f4) * rem);
                const float pbase = lzfwpm * klzp + lzfwsm * klzs;
                const float pz = fminf(lztwm + lzfwsm * (1.0f - klzs)
                                       + lzfwpm * (1.0f - klzp),
                                       100000.0f * pbase);
                const float inv_uztwm = frcp(uztwm);
                const float inv_uzfwm = frcp(uzfwm);
                const float inv_lztwm = frcp(lztwm);
                const float inv_uzsum = frcp(uztwm + uzfwm);
                const float inv_defmax = frcp(lztwm + lzfwpm + lzfwsm);
                db[0 * 64 + lane] = make_float2(uztwm, uzfwm);
                db[1 * 64 + lane] = make_float2(inv_uztwm, inv_uzfwm);
                db[2 * 64 + lane] = make_float2(inv_uzsum, lztwm);
                db[3 * 64 + lane] = make_float2(inv_lztwm, pbase);
                db[4 * 64 + lane] = make_float2(lzfwpm, lzfwsm);
                db[5 * 64 + lane] = make_float2(pz, inv_defmax);
            }
            asm volatile("s_waitcnt lgkmcnt(0)" ::: "memory");
            acc += plds[1920 + lane];
        }
    }
    asm volatile("" :: "v"(acc));
    if (wsok) ws[4096 + ((blockIdx.x * 64 + lane) & 4095)] = acc;
}

// ============ PROBE C: slim 7-row state math in isolation, x16 ============
__global__ __launch_bounds__(64, 1) void probe_state_slim(float* __restrict__ ws, int wsok)
{
    __shared__ __align__(16) float plds[5120];   // derived 4480 | smq 320 | sme 320

    const int lane = threadIdx.x;
    for (int k = lane; k < 5120; k += 64)
        plds[k] = 0.25f + (float)(k & 63) * 0.01f;
    asm volatile("s_waitcnt lgkmcnt(0)" ::: "memory");

    const float e1 = 2.0f + (float)(lane & 3) * 0.5f;
    const float pfree = 0.3f, pfree1m = 0.7f;
    const float klzp = 0.4f, klzs = 0.2f;

    float S1 = 0.001f, S2 = 0.001f, S3 = 0.001f, S4 = 0.001f, S5 = 0.001f;
    const float2* dregL = reinterpret_cast<const float2*>(plds);
    float* smq = plds + 4480;
    float* sme = plds + 4800;

    for (int rep = 0; rep < 16; ++rep) {
        for (int i = 0; i < 73; ++i) {
            asm volatile("" ::: "memory");
            RDSL(0) RDSL(1) RDSL(2) RDSL(3) RDSL(4)
            STEPL(0); STEPL(1); STEPL(2); STEPL(3); STEPL(4);
            asm volatile("s_waitcnt lgkmcnt(0)" ::: "memory");
        }
    }
    asm volatile("" :: "v"(S1), "v"(S2), "v"(S3), "v"(S4), "v"(S5));
    if (wsok) ws[8192 + ((blockIdx.x * 64 + lane) & 4095)] = S1 + S2 + S3 + S4 + S5;
}

extern "C" void kernel_launch(void* const* d_in, const int* in_sizes, int n_in,
                              void* d_out, int out_size, void* d_ws, size_t ws_size,
                              hipStream_t stream) {
    const float* x   = (const float*)d_in[0];   // (365, 4000, 3)
    const float* par = (const float*)d_in[1];   // (365, 4000, 11, 8)
    float* out = (float*)d_out;                 // (365, 4000, 2)

    sacsma_kernel<<<NGRID / 8, 192, 0, stream>>>(x, par, out);

    const int wsok = (ws_size >= (1u << 20)) ? 1 : 0;
    probe_skel<<<NGRID / 8, 192, 0, stream>>>(x, par, (float*)d_ws, wsok);
    probe_xform<<<NGRID / 8, 64, 0, stream>>>((float*)d_ws, wsok);
    probe_state_slim<<<NGRID / 8, 64, 0, stream>>>((float*)d_ws, wsok);
}

// Round 16
// 115.185 us; speedup vs baseline: 52.0834x; 52.0834x over previous
//
#include <hip/hip_runtime.h>
#include <stdint.h>

#define NSTEP 365
#define NGRID 4000
#define CAPMIN 0.00125f
#define SMINV 0.0001f
#define PSTR_DW (NGRID * 88)
#define XSTR_DW (NGRID * 3)

// r9 LDS layout (dwords), total 16000 dw = 64000 B
#define RAW_SLOT 384
#define RAW_REG  (5 * RAW_SLOT)
#define DER_BASE 7680
#define DER_SLOT 768
#define DER_REG  (5 * DER_SLOT)
#define SMQ_BASE 15360
#define SME_BASE 15680

typedef __attribute__((address_space(3))) uint32_t lds_u32_t;
typedef __attribute__((address_space(1))) uint32_t glb_u32_t;

__device__ __forceinline__ void dma4(const float* g, float* l) {
    __builtin_amdgcn_global_load_lds((const glb_u32_t*)(const void*)g,
                                     (lds_u32_t*)(void*)l, 4, 0, 0);
}

__device__ __forceinline__ float frcp(float x) { return __builtin_amdgcn_rcpf(x); }
__device__ __forceinline__ float fexp2(float x) { return __builtin_amdgcn_exp2f(x); }
__device__ __forceinline__ float flog2(float x) { return __builtin_amdgcn_logf(x); }

__device__ __forceinline__ void issue_slot(const float* pp, const float* px,
                                           int t, float* dst) {
    const float* pj = pp + (size_t)t * PSTR_DW;
    dma4(pj,      dst);
    dma4(pj + 8,  dst + 64);
    dma4(pj + 16, dst + 128);
    dma4(pj + 24, dst + 192);
    dma4(pj + 32, dst + 256);
    dma4(px + (size_t)t * XSTR_DW, dst + 320);
}

// ---- state wave: hoisted reads (r9 verbatim) ----
#define RDS(j)                                                               \
    const float  c0_##j = rreg[(j) * RAW_SLOT + lane];                       \
    const float  kz_##j = rreg[(j) * RAW_SLOT + 256 + lane];                 \
    const float  Pp_##j = rreg[(j) * RAW_SLOT + 320 + gl3];                  \
    const float  Ee_##j = rreg[(j) * RAW_SLOT + 322 + gl3];                  \
    const float2 dA_##j = dreg[(j) * 384 + lane];                            \
    const float2 dB_##j = dreg[(j) * 384 + 64 + lane];                       \
    const float2 dC_##j = dreg[(j) * 384 + 128 + lane];                      \
    const float2 dD_##j = dreg[(j) * 384 + 192 + lane];                      \
    const float2 dE_##j = dreg[(j) * 384 + 256 + lane];                      \
    const float2 dF_##j = dreg[(j) * 384 + 320 + lane];

#define STEP(j) do {                                                         \
    const float uztwm = dA_##j.x, uzfwm = dA_##j.y;                          \
    const float inv_uztwm = dB_##j.x, inv_uzfwm = dB_##j.y;                  \
    const float inv_uzsum = dC_##j.x, lztwm = dC_##j.y;                      \
    const float inv_lztwm = dD_##j.x, pbase = dD_##j.y;                      \
    const float lzfwpm = dE_##j.x, lzfwsm = dE_##j.y;                        \
    const float pz = dF_##j.x, inv_defmax = dF_##j.y;                        \
    const float Ep = Ee_##j, kuz = kz_##j;                                   \
    const float qdir = c0_##j * Pp_##j;                                      \
    const float peff = Pp_##j - qdir;                                        \
    const float rud  = S2 * uztwm - S1 * uzfwm;                              \
    const float ru   = (rud > 0.0f) ? rud * inv_uzsum : 0.0f;                \
    const float euztw = fminf(S1 * inv_uztwm * Ep, S1);                      \
    const float twexu = (S1 >= uztwm) ? peff : 0.0f;                         \
    const float qsur  = (S2 >= uzfwm) ? twexu : 0.0f;                        \
    const float qint  = kuz * S2;                                            \
    const float euzfw = fminf(fmaxf(0.0f, Ep - euztw), S2);                  \
    const float deficit = fmaxf(1e-8f, lztwm - S3)                           \
                        + fmaxf(1e-8f, lzfwpm - S4)                          \
                        + fmaxf(1e-8f, lzfwsm - S5);                         \
    const float powterm = fexp2(e1 * flog2(deficit * inv_defmax));           \
    const float pc = fminf((pbase + pz * powterm) * (S2 * inv_uzfwm), S2);   \
    const float pctw = (1.0f - pfree) * pc;                                  \
    const float ev3 = fmaxf(0.0f, Ep - euztw - euzfw);                       \
    const float elztw = fminf(S3 * inv_lztwm * ev3, S3);                     \
    const float twexl = (S3 >= lztwm) ? pctw : 0.0f;                         \
    const float aa = fmaxf(0.0f, lzfwpm - S4) * lzfwsm;                      \
    const float bb = fmaxf(0.0f, lzfwsm - S5) * lzfwpm;                      \
    const float den = aa + bb;                                               \
    const float pm = lzfwpm + lzfwsm;                                        \
    const float fp = ((den > 0.0f) ? aa : lzfwpm)                            \
                   * frcp((den > 0.0f) ? den : pm);                          \
    const float fs = 1.0f - fp;                                              \
    const float twexlp = fp * twexl, twexls = fs * twexl;                    \
    const float pcfwp = pfree * fp * pc, pcfws = pfree * fs * pc;            \
    const bool rlm = S3 * pm < (S4 + S5) * lztwm;                            \
    const float rlp = rlm ? (S4 * lztwm - S3 * lzfwpm) * inv_defmax : 0.0f;  \
    const float rls = rlm ? (S5 * lztwm - S3 * lzfwsm) * inv_defmax : 0.0f;  \
    const float qbfp = klzp * S4, qbfs = klzs * S5;                          \
    S1 = fmaxf(S1 + peff + ru - euztw - twexu, SMINV);                       \
    S2 = fmaxf(S2 + twexu - euzfw - qsur - qint - ru - pc, SMINV);           \
    S3 = fmaxf(S3 + pctw + rlp + rls - elztw - twexl, SMINV);                \
    S4 = fmaxf(S4 + twexlp + pcfwp - rlp - qbfp, SMINV);                     \
    S5 = fmaxf(S5 + twexls + pcfws - rls - qbfs, SMINV);                     \
    smq[(j) * 64 + lane] = qdir + qsur + qint + qbfp + qbfs;                 \
    sme[(j) * 64 + lane] = euztw + euzfw + elztw;                            \
} while (0)

__global__ __launch_bounds__(128, 1) void sacsma_kernel(
    const float* __restrict__ x,     // [NSTEP][NGRID][3]
    const float* __restrict__ par,   // [NSTEP][NGRID][11][8]
    float* __restrict__ out)         // [NSTEP][NGRID][2]
{
    __shared__ __align__(16) float lds[16000];   // 64000 B

    const int wave = threadIdx.x >> 6;
    const int lane = threadIdx.x & 63;
    const int g0   = blockIdx.x * 8;
    const int gl   = lane >> 3;
    const int mu   = lane & 7;
    const int g    = g0 + gl;
    const int gl3  = gl * 3;

    if (wave == 0) {
        // ===== merged producer + transform wave =====
        // producer pointers
        const float* pp = par + (size_t)g * 88 + mu;
        int xl = lane; if (xl >= 24) xl -= 24; if (xl >= 24) xl -= 24;
        const int xq = xl / 3;
        const float* px = x + (g0 + xq) * 3 + (xl - xq * 3);
        // transform statics
        const float* ps = par + ((size_t)(NSTEP - 1) * NGRID + g) * 88 + mu;
        const float f3   = 0.005f + ps[6 * 8] * 0.99f;
        const float f4   = 0.005f + ps[7 * 8] * 0.99f;
        const float klzp = ps[9 * 8];
        const float klzs = ps[10 * 8];

        // prologue: batch 0 -> raw region 0
        #pragma unroll
        for (int j = 0; j < 5; ++j)
            issue_slot(pp, px, j, lds + j * RAW_SLOT);

        for (int i = 0; i < 75; ++i) {
            // (a) issue next batch FIRST — latency hides under transform below
            if (i <= 71) {
                const int b = i + 1;                   // batches 1..72
                float* dst = lds + (b & 3) * RAW_REG;
                const int tb = 5 * b;
                #pragma unroll
                for (int j = 0; j < 5; ++j)
                    issue_slot(pp, px, tb + j, dst + j * RAW_SLOT);
            }
            // (b) transform batch i-1: raw (i-1)&3 -> derived (i-1)&1
            if (i >= 1 && i <= 73) {
                const int b = i - 1;                   // batches 0..72
                const float* rreg = lds + (b & 3) * RAW_REG;
                float* dregf = lds + DER_BASE + (b & 1) * DER_REG;
                #pragma unroll
                for (int j = 0; j < 5; ++j) {
                    const float* rb = rreg + j * RAW_SLOT;
                    float2* db = reinterpret_cast<float2*>(dregf + j * DER_SLOT);
                    const float c1 = rb[64 + lane];
                    const float c2 = rb[128 + lane];
                    const float c3 = rb[192 + lane];
                    const float smaxv = 1.0f + c1 * 1999.0f;
                    const float f1 = 0.005f + c2 * 0.99f;
                    const float f2 = 0.005f + c3 * 0.99f;
                    const float uztwm = f1 * smaxv;
                    float rem = smaxv - uztwm;
                    const float uzfwm = fmaxf(CAPMIN, f2 * rem);
                    rem -= uzfwm;
                    const float lztwm = fmaxf(CAPMIN, f3 * rem);
                    rem -= lztwm;
                    const float lzfwpm = fmaxf(CAPMIN, f4 * rem);
                    const float lzfwsm = fmaxf(CAPMIN, (1.0f - f4) * rem);
                    const float pbase = lzfwpm * klzp + lzfwsm * klzs;
                    const float pz = fminf(lztwm + lzfwsm * (1.0f - klzs)
                                           + lzfwpm * (1.0f - klzp),
                                           100000.0f * pbase);
                    const float inv_uztwm = frcp(uztwm);
                    const float inv_uzfwm = frcp(uzfwm);
                    const float inv_lztwm = frcp(lztwm);
                    const float inv_uzsum = frcp(uztwm + uzfwm);
                    const float inv_defmax = frcp(lztwm + lzfwpm + lzfwsm);
                    db[0 * 64 + lane] = make_float2(uztwm, uzfwm);
                    db[1 * 64 + lane] = make_float2(inv_uztwm, inv_uzfwm);
                    db[2 * 64 + lane] = make_float2(inv_uzsum, lztwm);
                    db[3 * 64 + lane] = make_float2(inv_lztwm, pbase);
                    db[4 * 64 + lane] = make_float2(lzfwpm, lzfwsm);
                    db[5 * 64 + lane] = make_float2(pz, inv_defmax);
                }
            }
            // (c) counted wait: batch i retired; only batch i+1's 30 remain
            if (i <= 71) {
                asm volatile("s_waitcnt vmcnt(30)" ::: "memory");
            } else {
                asm volatile("s_waitcnt vmcnt(0)" ::: "memory");
            }
            asm volatile("s_waitcnt lgkmcnt(0)" ::: "memory");
            asm volatile("s_barrier" ::: "memory");
        }
    } else {
        // ===== state wave: r9 verbatim =====
        const float* ps = par + ((size_t)(NSTEP - 1) * NGRID + g) * 88 + mu;
        const float e1    = 1.0f + ps[5 * 8] * 7.0f;
        const float pfree = ps[8 * 8];
        const float klzp  = ps[9 * 8];
        const float klzs  = ps[10 * 8];

        float S1 = 0.001f, S2 = 0.001f, S3 = 0.001f, S4 = 0.001f, S5 = 0.001f;
        float* smq = lds + SMQ_BASE;
        float* sme = lds + SME_BASE;

        for (int i = 0; i < 75; ++i) {
            if (i >= 2) {
                const int b = i - 2;                   // batches 0..72
                const float* rreg = lds + (b & 3) * RAW_REG;
                const float2* dreg = reinterpret_cast<const float2*>(
                    lds + DER_BASE + (b & 1) * DER_REG);

                RDS(0) RDS(1) RDS(2) RDS(3) RDS(4)
                STEP(0); STEP(1); STEP(2); STEP(3); STEP(4);

                if (lane < 40) {
                    const int s  = lane >> 3;
                    const int gg = lane & 7;
                    const float4* q4 = reinterpret_cast<const float4*>(&smq[s * 64 + gg * 8]);
                    const float4* e4 = reinterpret_cast<const float4*>(&sme[s * 64 + gg * 8]);
                    const float4 qa = q4[0], qb = q4[1];
                    const float4 ea = e4[0], eb = e4[1];
                    const float qsum = ((qa.x + qa.y) + (qa.z + qa.w))
                                     + ((qb.x + qb.y) + (qb.z + qb.w));
                    const float esum = ((ea.x + ea.y) + (ea.z + ea.w))
                                     + ((eb.x + eb.y) + (eb.z + eb.w));
                    float2 o = make_float2(qsum * 0.125f, esum * 0.125f);
                    *reinterpret_cast<float2*>(
                        out + ((size_t)(5 * b + s) * NGRID + g0 + gg) * 2) = o;
                }
            }
            asm volatile("s_barrier" ::: "memory");
        }
    }
}

extern "C" void kernel_launch(void* const* d_in, const int* in_sizes, int n_in,
                              void* d_out, int out_size, void* d_ws, size_t ws_size,
                              hipStream_t stream) {
    const float* x   = (const float*)d_in[0];   // (365, 4000, 3)
    const float* par = (const float*)d_in[1];   // (365, 4000, 11, 8)
    float* out = (float*)d_out;                 // (365, 4000, 2)

    sacsma_kernel<<<NGRID / 8, 128, 0, stream>>>(x, par, out);  // 500 WGs x 2 waves
}